// Round 1
// baseline (269.812 us; speedup 1.0000x reference)
//
#include <hip/hip_runtime.h>
#include <math.h>

// CAGroup3DHead: exploit (a) dead `voted` branch, (b) sem_prob>0.15 gating
// that zeroes ~all rows exactly (bias -4.595, logit std ~0.226 -> +12.7 sigma
// needed to activate). Compute masks; zero output; run full fp32 chain only
// on dynamically-active rows (correct for any input, ~0 rows in practice).

#define NCH   128
#define NCLS_ 10
#define KNBR  27
#define THRV  0.15f

__device__ __forceinline__ float elu1(float x) {
    return x > 0.0f ? x : expm1f(x);
}

// ---------------------------------------------------------------------------
// Kernel 1: sem logits -> sigmoid -> per-row 10-bit active mask.
// One wave (64 lanes) per row; Wsem transposed in LDS (2-way bank alias = free).
// ---------------------------------------------------------------------------
__global__ __launch_bounds__(256) void sem_mask_kernel(
    const float* __restrict__ feats,      // [N, 128]
    const float* __restrict__ Wsem,       // [128, 10]
    const float* __restrict__ bsem,       // [10]
    unsigned int* __restrict__ maskbits,  // [N] out
    int N)
{
    __shared__ float WsT[NCLS_ * NCH];    // [c][j]
    __shared__ float bs[NCLS_];
    for (int idx = threadIdx.x; idx < NCLS_ * NCH; idx += blockDim.x) {
        int j = idx / NCLS_, c = idx % NCLS_;
        WsT[c * NCH + j] = Wsem[idx];
    }
    if (threadIdx.x < NCLS_) bs[threadIdx.x] = bsem[threadIdx.x];
    __syncthreads();

    const int wave = threadIdx.x >> 6;
    const int lane = threadIdx.x & 63;
    const int row  = blockIdx.x * 4 + wave;
    if (row >= N) return;

    const float2 f2 = *(const float2*)(feats + (size_t)row * NCH + 2 * lane);
    float acc[NCLS_];
#pragma unroll
    for (int c = 0; c < NCLS_; ++c)
        acc[c] = f2.x * WsT[c * NCH + 2 * lane] + f2.y * WsT[c * NCH + 2 * lane + 1];
#pragma unroll
    for (int c = 0; c < NCLS_; ++c) {
#pragma unroll
        for (int off = 32; off > 0; off >>= 1)
            acc[c] += __shfl_xor(acc[c], off);
    }
    if (lane == 0) {
        unsigned int bits = 0u;
#pragma unroll
        for (int c = 0; c < NCLS_; ++c) {
            float s = acc[c] + bs[c];
            float p = 1.0f / (1.0f + expf(-s));
            if (p > THRV) bits |= (1u << c);
        }
        maskbits[row] = bits;
    }
}

// ---------------------------------------------------------------------------
// Kernel 2: per (class, 256-row chunk): zero-fill the contiguous output span,
// then run the full chain for any active row (both halves: i and i+N).
// All branches on maskbits are block-uniform -> __syncthreads is safe.
// ---------------------------------------------------------------------------
__global__ __launch_bounds__(256) void chain_kernel(
    const float* __restrict__ feats, const int* __restrict__ nbr,
    const unsigned int* __restrict__ maskbits,
    const float* __restrict__ fo_w, const float* __restrict__ fo_g, const float* __restrict__ fo_b,
    const float* __restrict__ cls_out_w, const float* __restrict__ cls_out_g, const float* __restrict__ cls_out_b,
    const float* __restrict__ up_w, const float* __restrict__ up_g, const float* __restrict__ up_b,
    const float* __restrict__ fuse_w, const float* __restrict__ fuse_g, const float* __restrict__ fuse_b,
    const float* __restrict__ exp_w, const float* __restrict__ exp_g, const float* __restrict__ exp_b,
    const float* __restrict__ ctr_w, const float* __restrict__ reg_w,
    const float* __restrict__ cls_w, const float* __restrict__ cls_b,
    const float* __restrict__ scales,
    float* __restrict__ out, int N, int chunks)
{
    const int c     = blockIdx.x / chunks;
    const int chunk = blockIdx.x % chunks;
    const int i0    = chunk * 256;
    const int tid   = threadIdx.x;

    // --- zero-fill this block's two contiguous 256*17-float spans (16B aligned) ---
    {
        const size_t base1 = ((size_t)c * 2 * N + i0) * 17;
        const size_t base2 = ((size_t)c * 2 * N + N + i0) * 17;
        float4 z4 = make_float4(0.f, 0.f, 0.f, 0.f);
        float4* p1 = (float4*)(out + base1);
        float4* p2 = (float4*)(out + base2);
        const int n4 = 256 * 17 / 4;  // 1088
        for (int idx = tid; idx < n4; idx += 256) { p1[idx] = z4; p2[idx] = z4; }
    }
    __syncthreads();

    __shared__ float xs[NCH];
    __shared__ float xin[2][NCH];
    __shared__ float hbuf[2][NCH];
    __shared__ float ubuf[2][NCH];
    __shared__ float fbuf[2][NCH];
    __shared__ float ebuf[2][NCH];

    const int h = tid >> 7;   // 0: offset-features half, 1: feats half
    const int t = tid & 127;  // output channel

    for (int i = i0; i < i0 + 256; ++i) {
        const unsigned int bits = maskbits[i];
        if (!((bits >> c) & 1u)) continue;  // block-uniform

        // ---- offset_features row i: 27-neighbor sparse conv + BN + ELU ----
        float acc = 0.0f;
        for (int k = 0; k < KNBR; ++k) {
            if (tid < NCH) {
                const int nb = nbr[(size_t)i * KNBR + k];
                xs[tid] = feats[(size_t)nb * NCH + tid];
            }
            __syncthreads();
            if (tid < NCH) {
                const float* Wk = fo_w + (size_t)k * NCH * NCH;
#pragma unroll 8
                for (int j = 0; j < NCH; ++j)
                    acc += xs[j] * Wk[j * NCH + tid];
            }
            __syncthreads();
        }
        if (tid < NCH) xin[0][tid] = elu1(acc * fo_g[tid] + fo_b[tid]);
        else           xin[1][t]   = feats[(size_t)i * NCH + t];
        __syncthreads();

        // ---- layer 1: cls_out ----
        {
            const float* W = cls_out_w + (size_t)c * NCH * NCH;
            float v = 0.0f;
#pragma unroll 8
            for (int j = 0; j < NCH; ++j) v += xin[h][j] * W[j * NCH + t];
            v = elu1(v * cls_out_g[c * NCH + t] + cls_out_b[c * NCH + t]);
            hbuf[h][t] = v;
        }
        __syncthreads();
        // ---- layer 2: up ----
        {
            const float* W = up_w + (size_t)c * NCH * NCH;
            float v = 0.0f;
#pragma unroll 8
            for (int j = 0; j < NCH; ++j) v += hbuf[h][j] * W[j * NCH + t];
            v = elu1(v * up_g[c * NCH + t] + up_b[c * NCH + t]);
            ubuf[h][t] = v;
        }
        __syncthreads();
        // ---- layer 3: fuse (concat[hc, uc] @ W3) ----
        {
            const float* W = fuse_w + (size_t)c * 2 * NCH * NCH;
            float v = 0.0f;
#pragma unroll 8
            for (int j = 0; j < NCH; ++j) v += hbuf[h][j] * W[j * NCH + t];
#pragma unroll 8
            for (int j = 0; j < NCH; ++j) v += ubuf[h][j] * W[(NCH + j) * NCH + t];
            v = elu1(v * fuse_g[c * NCH + t] + fuse_b[c * NCH + t]);
            fbuf[h][t] = v;
        }
        __syncthreads();
        // ---- layer 4: expand ----
        {
            const float* W = exp_w + (size_t)c * NCH * NCH;
            float v = 0.0f;
#pragma unroll 8
            for (int j = 0; j < NCH; ++j) v += fbuf[h][j] * W[j * NCH + t];
            v = elu1(v * exp_g[c * NCH + t] + exp_b[c * NCH + t]);
            ebuf[h][t] = v;
        }
        __syncthreads();
        // ---- heads: [ctr(1), reg(6), cls(10)] = 17 ----
        if (t < 17) {
            float a = 0.0f;
            if (t == 0) {
                for (int j = 0; j < NCH; ++j) a += ebuf[h][j] * ctr_w[j];
            } else if (t < 7) {
                const int r = t - 1;
                for (int j = 0; j < NCH; ++j) a += ebuf[h][j] * reg_w[j * 6 + r];
                a = expf(scales[c] * a);
            } else {
                const int q = t - 7;
                for (int j = 0; j < NCH; ++j) a += ebuf[h][j] * cls_w[j * NCLS_ + q];
                a += cls_b[q];
            }
            out[((size_t)c * 2 * N + (size_t)h * N + i) * 17 + t] = a;
        }
        __syncthreads();
    }
}

extern "C" void kernel_launch(void* const* d_in, const int* in_sizes, int n_in,
                              void* d_out, int out_size, void* d_ws, size_t ws_size,
                              hipStream_t stream) {
    // setup_inputs() order:
    //  0 coords (unused)  1 feats  2 nbr  3 Wsem  4 bsem
    //  5..11 offset block (dead code: `voted` is deleted)
    // 12 fo_w 13 fo_g 14 fo_b
    // 15 cls_out_w 16 cls_out_g 17 cls_out_b
    // 18 up_w 19 up_g 20 up_b
    // 21 fuse_w 22 fuse_g 23 fuse_b
    // 24 exp_w 25 exp_g 26 exp_b
    // 27 ctr_w 28 reg_w 29 cls_w 30 cls_b 31 scales
    const float* feats = (const float*)d_in[1];
    const int*   nbr   = (const int*)d_in[2];
    const float* Wsem  = (const float*)d_in[3];
    const float* bsem  = (const float*)d_in[4];
    const float* fo_w  = (const float*)d_in[12];
    const float* fo_g  = (const float*)d_in[13];
    const float* fo_b  = (const float*)d_in[14];
    const float* cls_out_w = (const float*)d_in[15];
    const float* cls_out_g = (const float*)d_in[16];
    const float* cls_out_b = (const float*)d_in[17];
    const float* up_w  = (const float*)d_in[18];
    const float* up_g  = (const float*)d_in[19];
    const float* up_b  = (const float*)d_in[20];
    const float* fuse_w = (const float*)d_in[21];
    const float* fuse_g = (const float*)d_in[22];
    const float* fuse_b = (const float*)d_in[23];
    const float* exp_w = (const float*)d_in[24];
    const float* exp_g = (const float*)d_in[25];
    const float* exp_b = (const float*)d_in[26];
    const float* ctr_w = (const float*)d_in[27];
    const float* reg_w = (const float*)d_in[28];
    const float* cls_w = (const float*)d_in[29];
    const float* cls_b = (const float*)d_in[30];
    const float* scales = (const float*)d_in[31];

    const int N = in_sizes[1] / NCH;      // 65536
    unsigned int* maskbits = (unsigned int*)d_ws;  // N * 4 B = 256 KB
    float* out = (float*)d_out;

    const int chunks = N / 256;           // 256

    sem_mask_kernel<<<dim3((N + 3) / 4), dim3(256), 0, stream>>>(
        feats, Wsem, bsem, maskbits, N);

    chain_kernel<<<dim3(NCLS_ * chunks), dim3(256), 0, stream>>>(
        feats, nbr, maskbits,
        fo_w, fo_g, fo_b,
        cls_out_w, cls_out_g, cls_out_b,
        up_w, up_g, up_b,
        fuse_w, fuse_g, fuse_b,
        exp_w, exp_g, exp_b,
        ctr_w, reg_w, cls_w, cls_b, scales,
        out, N, chunks);
}

// Round 2
// 186.798 us; speedup vs baseline: 1.4444x; 1.4444x over previous
//
#include <hip/hip_runtime.h>
#include <math.h>

// CAGroup3DHead: (a) `voted`/offset-MLP branch is dead code; (b) sem gating
// (sigmoid(logit) > 0.15 with bias -4.595, logit sigma ~0.23) needs +12.7
// sigma -> ~zero active rows; masked rows are EXACT zeros in the reference
// (input zeroed before matmuls AND output multiplied by mask).
// Strategy: fast mask computation, zero-fill output at write BW, run the full
// fp32 chain only for dynamically-active rows (correct for any input).

#define NCH   128
#define NCLS_ 10
#define KNBR  27
#define THRV  0.15f

__device__ __forceinline__ float elu1(float x) {
    return x > 0.0f ? x : expm1f(x);
}

// ---------------------------------------------------------------------------
// Kernel 1: per-row 10-class logits -> 10-bit active mask.
// Block = 64 rows. Wave w owns j-chunk [32w, 32w+32): weight indices are
// wave-uniform (readfirstlane) -> scalar s_load path, no LDS for weights.
// Lane = row -> feats read as 8 float4 per lane. Partials reduced via LDS.
// ---------------------------------------------------------------------------
__global__ __launch_bounds__(256) void mask_kernel(
    const float* __restrict__ feats,      // [N, 128]
    const float* __restrict__ Wsem,       // [128, 10]
    const float* __restrict__ bsem,       // [10]
    unsigned int* __restrict__ maskbits,  // [N] out
    int N)
{
    __shared__ float part[4][64][11];     // [wave][row][class], pad 11: <=2-way

    const int tid  = threadIdx.x;
    const int lane = tid & 63;
    const int w    = __builtin_amdgcn_readfirstlane(tid >> 6);  // wave-uniform
    const int r0   = blockIdx.x * 64;
    const int row  = r0 + lane;

    if (row < N) {
        // load this lane's 32-float j-chunk of its row
        const float* fp = feats + (size_t)row * NCH + w * 32;
        float fr[32];
#pragma unroll
        for (int k = 0; k < 8; ++k) {
            const float4 v = ((const float4*)fp)[k];
            fr[4 * k + 0] = v.x; fr[4 * k + 1] = v.y;
            fr[4 * k + 2] = v.z; fr[4 * k + 3] = v.w;
        }
        const float* wp = Wsem + (size_t)(w * 32) * NCLS_;  // uniform base
        float acc[NCLS_];
#pragma unroll
        for (int c = 0; c < NCLS_; ++c) acc[c] = 0.0f;
#pragma unroll
        for (int jj = 0; jj < 32; ++jj) {
            const float fv = fr[jj];
            const float* wrow = wp + jj * NCLS_;            // uniform -> s_load
#pragma unroll
            for (int c = 0; c < NCLS_; ++c) acc[c] += fv * wrow[c];
        }
#pragma unroll
        for (int c = 0; c < NCLS_; ++c) part[w][lane][c] = acc[c];
    }
    __syncthreads();

    if (tid < 64 && r0 + tid < N) {
        unsigned int bits = 0u;
#pragma unroll
        for (int c = 0; c < NCLS_; ++c) {
            const float s = part[0][tid][c] + part[1][tid][c]
                          + part[2][tid][c] + part[3][tid][c] + bsem[c];
            const float p = 1.0f / (1.0f + expf(-s));
            if (p > THRV) bits |= (1u << c);
        }
        maskbits[r0 + tid] = bits;
    }
}

// ---------------------------------------------------------------------------
// Kernel 2: per (class, 256-row chunk): zero-fill the contiguous output span,
// ballot-check the 256 mask words (one coalesced 1KB load), early-exit if no
// row is active; otherwise run the full chain for active rows (rare path).
// ---------------------------------------------------------------------------
__global__ __launch_bounds__(256) void chain_kernel(
    const float* __restrict__ feats, const int* __restrict__ nbr,
    const unsigned int* __restrict__ maskbits,
    const float* __restrict__ fo_w, const float* __restrict__ fo_g, const float* __restrict__ fo_b,
    const float* __restrict__ cls_out_w, const float* __restrict__ cls_out_g, const float* __restrict__ cls_out_b,
    const float* __restrict__ up_w, const float* __restrict__ up_g, const float* __restrict__ up_b,
    const float* __restrict__ fuse_w, const float* __restrict__ fuse_g, const float* __restrict__ fuse_b,
    const float* __restrict__ exp_w, const float* __restrict__ exp_g, const float* __restrict__ exp_b,
    const float* __restrict__ ctr_w, const float* __restrict__ reg_w,
    const float* __restrict__ cls_w, const float* __restrict__ cls_b,
    const float* __restrict__ scales,
    float* __restrict__ out, int N, int chunks)
{
    const int c     = blockIdx.x / chunks;
    const int chunk = blockIdx.x % chunks;
    const int i0    = chunk * 256;
    const int tid   = threadIdx.x;

    // --- zero-fill this block's two contiguous 256*17-float spans (16B aligned) ---
    {
        const size_t base1 = ((size_t)c * 2 * N + i0) * 17;
        const size_t base2 = ((size_t)c * 2 * N + N + i0) * 17;
        float4 z4 = make_float4(0.f, 0.f, 0.f, 0.f);
        float4* p1 = (float4*)(out + base1);
        float4* p2 = (float4*)(out + base2);
        const int n4 = 256 * 17 / 4;  // 1088
        for (int idx = tid; idx < n4; idx += 256) { p1[idx] = z4; p2[idx] = z4; }
    }

    // --- fast activity check: one coalesced load + ballot + 4-word OR ---
    __shared__ unsigned long long wball[4];
    {
        const unsigned int mb = maskbits[i0 + tid];
        const unsigned long long bal = __ballot(((mb >> c) & 1u) != 0u);
        if ((tid & 63) == 0) wball[tid >> 6] = bal;
    }
    __syncthreads();
    const unsigned long long any = wball[0] | wball[1] | wball[2] | wball[3];
    if (any == 0ULL) return;  // block-uniform: the overwhelmingly common case

    // ---------------- rare path: some row in this chunk is active ----------------
    __shared__ float xs[NCH];
    __shared__ float xin[2][NCH];
    __shared__ float hbuf[2][NCH];
    __shared__ float ubuf[2][NCH];
    __shared__ float fbuf[2][NCH];
    __shared__ float ebuf[2][NCH];

    const int h = tid >> 7;   // 0: offset-features half, 1: feats half
    const int t = tid & 127;  // output channel

    for (int i = i0; i < i0 + 256; ++i) {
        const unsigned int bits = maskbits[i];
        if (!((bits >> c) & 1u)) continue;  // block-uniform

        // ---- offset_features row i: 27-neighbor sparse conv + BN + ELU ----
        float acc = 0.0f;
        for (int k = 0; k < KNBR; ++k) {
            if (tid < NCH) {
                const int nb = nbr[(size_t)i * KNBR + k];
                xs[tid] = feats[(size_t)nb * NCH + tid];
            }
            __syncthreads();
            if (tid < NCH) {
                const float* Wk = fo_w + (size_t)k * NCH * NCH;
#pragma unroll 8
                for (int j = 0; j < NCH; ++j)
                    acc += xs[j] * Wk[j * NCH + tid];
            }
            __syncthreads();
        }
        if (tid < NCH) xin[0][tid] = elu1(acc * fo_g[tid] + fo_b[tid]);
        else           xin[1][t]   = feats[(size_t)i * NCH + t];
        __syncthreads();

        // ---- layer 1: cls_out ----
        {
            const float* W = cls_out_w + (size_t)c * NCH * NCH;
            float v = 0.0f;
#pragma unroll 8
            for (int j = 0; j < NCH; ++j) v += xin[h][j] * W[j * NCH + t];
            v = elu1(v * cls_out_g[c * NCH + t] + cls_out_b[c * NCH + t]);
            hbuf[h][t] = v;
        }
        __syncthreads();
        // ---- layer 2: up ----
        {
            const float* W = up_w + (size_t)c * NCH * NCH;
            float v = 0.0f;
#pragma unroll 8
            for (int j = 0; j < NCH; ++j) v += hbuf[h][j] * W[j * NCH + t];
            v = elu1(v * up_g[c * NCH + t] + up_b[c * NCH + t]);
            ubuf[h][t] = v;
        }
        __syncthreads();
        // ---- layer 3: fuse (concat[hc, uc] @ W3) ----
        {
            const float* W = fuse_w + (size_t)c * 2 * NCH * NCH;
            float v = 0.0f;
#pragma unroll 8
            for (int j = 0; j < NCH; ++j) v += hbuf[h][j] * W[j * NCH + t];
#pragma unroll 8
            for (int j = 0; j < NCH; ++j) v += ubuf[h][j] * W[(NCH + j) * NCH + t];
            v = elu1(v * fuse_g[c * NCH + t] + fuse_b[c * NCH + t]);
            fbuf[h][t] = v;
        }
        __syncthreads();
        // ---- layer 4: expand ----
        {
            const float* W = exp_w + (size_t)c * NCH * NCH;
            float v = 0.0f;
#pragma unroll 8
            for (int j = 0; j < NCH; ++j) v += fbuf[h][j] * W[j * NCH + t];
            v = elu1(v * exp_g[c * NCH + t] + exp_b[c * NCH + t]);
            ebuf[h][t] = v;
        }
        __syncthreads();
        // ---- heads: [ctr(1), reg(6), cls(10)] = 17 ----
        if (t < 17) {
            float a = 0.0f;
            if (t == 0) {
                for (int j = 0; j < NCH; ++j) a += ebuf[h][j] * ctr_w[j];
            } else if (t < 7) {
                const int r = t - 1;
                for (int j = 0; j < NCH; ++j) a += ebuf[h][j] * reg_w[j * 6 + r];
                a = expf(scales[c] * a);
            } else {
                const int q = t - 7;
                for (int j = 0; j < NCH; ++j) a += ebuf[h][j] * cls_w[j * NCLS_ + q];
                a += cls_b[q];
            }
            out[((size_t)c * 2 * N + (size_t)h * N + i) * 17 + t] = a;
        }
        __syncthreads();
    }
}

extern "C" void kernel_launch(void* const* d_in, const int* in_sizes, int n_in,
                              void* d_out, int out_size, void* d_ws, size_t ws_size,
                              hipStream_t stream) {
    // setup_inputs() order:
    //  0 coords (unused)  1 feats  2 nbr  3 Wsem  4 bsem
    //  5..11 offset block (dead code: `voted` is deleted)
    // 12 fo_w 13 fo_g 14 fo_b  15-17 cls_out_*  18-20 up_*  21-23 fuse_*
    // 24-26 exp_*  27 ctr_w 28 reg_w 29 cls_w 30 cls_b 31 scales
    const float* feats = (const float*)d_in[1];
    const int*   nbr   = (const int*)d_in[2];
    const float* Wsem  = (const float*)d_in[3];
    const float* bsem  = (const float*)d_in[4];
    const float* fo_w  = (const float*)d_in[12];
    const float* fo_g  = (const float*)d_in[13];
    const float* fo_b  = (const float*)d_in[14];
    const float* cls_out_w = (const float*)d_in[15];
    const float* cls_out_g = (const float*)d_in[16];
    const float* cls_out_b = (const float*)d_in[17];
    const float* up_w  = (const float*)d_in[18];
    const float* up_g  = (const float*)d_in[19];
    const float* up_b  = (const float*)d_in[20];
    const float* fuse_w = (const float*)d_in[21];
    const float* fuse_g = (const float*)d_in[22];
    const float* fuse_b = (const float*)d_in[23];
    const float* exp_w = (const float*)d_in[24];
    const float* exp_g = (const float*)d_in[25];
    const float* exp_b = (const float*)d_in[26];
    const float* ctr_w = (const float*)d_in[27];
    const float* reg_w = (const float*)d_in[28];
    const float* cls_w = (const float*)d_in[29];
    const float* cls_b = (const float*)d_in[30];
    const float* scales = (const float*)d_in[31];

    const int N = in_sizes[1] / NCH;      // 65536
    unsigned int* maskbits = (unsigned int*)d_ws;  // N * 4 B = 256 KB
    float* out = (float*)d_out;

    const int chunks = N / 256;           // 256

    mask_kernel<<<dim3((N + 63) / 64), dim3(256), 0, stream>>>(
        feats, Wsem, bsem, maskbits, N);

    chain_kernel<<<dim3(NCLS_ * chunks), dim3(256), 0, stream>>>(
        feats, nbr, maskbits,
        fo_w, fo_g, fo_b,
        cls_out_w, cls_out_g, cls_out_b,
        up_w, up_g, up_b,
        fuse_w, fuse_g, fuse_b,
        exp_w, exp_g, exp_b,
        ctr_w, reg_w, cls_w, cls_b, scales,
        out, N, chunks);
}

// Round 3
// 185.205 us; speedup vs baseline: 1.4568x; 1.0086x over previous
//
#include <hip/hip_runtime.h>
#include <math.h>

// CAGroup3DHead, fully fused single kernel.
// Facts exploited (verified R0-R2, absmax==0):
//  (a) `voted`/offset-MLP branch is dead code (del voted).
//  (b) sem gating sigmoid(logit)>0.15 with bias -4.595 needs a +12.7-sigma
//      logit -> ~zero active rows; masked rows are EXACT zeros in the
//      reference (inputs zeroed before matmuls AND outputs multiplied by m2).
// One block = one 64-row chunk: zero-fill its 20 output spans, compute its
// own 64x10 logits (wave-uniform scalar Wsem loads), block-uniform early
// exit; full fp32 chain only for dynamically-active (class,row) pairs.

#define NCH   128
#define NCLS_ 10
#define KNBR  27
#define THRV  0.15f
#define ROWS  64

__device__ __forceinline__ float elu1(float x) {
    return x > 0.0f ? x : expm1f(x);
}

__global__ __launch_bounds__(256) void fused_kernel(
    const float* __restrict__ feats, const int* __restrict__ nbr,
    const float* __restrict__ Wsem, const float* __restrict__ bsem,
    const float* __restrict__ fo_w, const float* __restrict__ fo_g, const float* __restrict__ fo_b,
    const float* __restrict__ cls_out_w, const float* __restrict__ cls_out_g, const float* __restrict__ cls_out_b,
    const float* __restrict__ up_w, const float* __restrict__ up_g, const float* __restrict__ up_b,
    const float* __restrict__ fuse_w, const float* __restrict__ fuse_g, const float* __restrict__ fuse_b,
    const float* __restrict__ exp_w, const float* __restrict__ exp_g, const float* __restrict__ exp_b,
    const float* __restrict__ ctr_w, const float* __restrict__ reg_w,
    const float* __restrict__ cls_w, const float* __restrict__ cls_b,
    const float* __restrict__ scales,
    float* __restrict__ out, int N)
{
    const int i0  = blockIdx.x * ROWS;
    const int tid = threadIdx.x;

    __shared__ float part[4][ROWS][11];   // [wave][row][class], pad 11
    __shared__ unsigned int rowbits[ROWS];
    __shared__ unsigned int anyword;

    if (tid == 0) anyword = 0u;

    // ---- 1) zero-fill this chunk's 20 output spans (each 64*17 floats, 16B aligned) ----
    {
        const float4 z4 = make_float4(0.f, 0.f, 0.f, 0.f);
#pragma unroll
        for (int s = 0; s < 2 * NCLS_; ++s) {
            const int c = s >> 1, h = s & 1;
            float4* p = (float4*)(out + ((size_t)c * 2 * N + (size_t)h * N + i0) * 17);
            for (int idx = tid; idx < ROWS * 17 / 4; idx += 256) p[idx] = z4;  // 272 f4
        }
    }

    // ---- 2) logits for 64 rows: wave w owns j-chunk [32w,32w+32) (uniform -> s_load) ----
    {
        const int lane = tid & 63;
        const int w    = __builtin_amdgcn_readfirstlane(tid >> 6);
        const int row  = i0 + lane;
        const float* fp = feats + (size_t)row * NCH + w * 32;
        float fr[32];
#pragma unroll
        for (int k = 0; k < 8; ++k) {
            const float4 v = ((const float4*)fp)[k];
            fr[4 * k + 0] = v.x; fr[4 * k + 1] = v.y;
            fr[4 * k + 2] = v.z; fr[4 * k + 3] = v.w;
        }
        const float* wp = Wsem + (size_t)(w * 32) * NCLS_;
        float acc[NCLS_];
#pragma unroll
        for (int c = 0; c < NCLS_; ++c) acc[c] = 0.0f;
#pragma unroll
        for (int jj = 0; jj < 32; ++jj) {
            const float fv = fr[jj];
            const float* wrow = wp + jj * NCLS_;
#pragma unroll
            for (int c = 0; c < NCLS_; ++c) acc[c] += fv * wrow[c];
        }
#pragma unroll
        for (int c = 0; c < NCLS_; ++c) part[w][lane][c] = acc[c];
    }
    __syncthreads();

    // ---- 3) reduce -> per-row bits, block OR ----
    if (tid < ROWS) {
        unsigned int bits = 0u;
#pragma unroll
        for (int c = 0; c < NCLS_; ++c) {
            const float s = part[0][tid][c] + part[1][tid][c]
                          + part[2][tid][c] + part[3][tid][c] + bsem[c];
            const float p = 1.0f / (1.0f + expf(-s));
            if (p > THRV) bits |= (1u << c);
        }
        rowbits[tid] = bits;
        if (bits) atomicOr(&anyword, bits);
    }
    __syncthreads();
    const unsigned int any = anyword;
    if (any == 0u) return;   // block-uniform: the overwhelmingly common case

    // -------------- rare path: some (class,row) in this chunk is active --------------
    __shared__ float xs[NCH];
    __shared__ float xin[2][NCH];
    __shared__ float hbuf[2][NCH];
    __shared__ float ubuf[2][NCH];
    __shared__ float fbuf[2][NCH];
    __shared__ float ebuf[2][NCH];

    const int h = tid >> 7;   // 0: offset-features half, 1: feats half
    const int t = tid & 127;  // output channel

    for (int c = 0; c < NCLS_; ++c) {
        if (!((any >> c) & 1u)) continue;            // uniform
        for (int r = 0; r < ROWS; ++r) {
            if (!((rowbits[r] >> c) & 1u)) continue; // uniform (LDS broadcast)
            const int i = i0 + r;

            // ---- offset_features row i: 27-neighbor sparse conv + BN + ELU ----
            float acc = 0.0f;
            for (int k = 0; k < KNBR; ++k) {
                if (tid < NCH) {
                    const int nb = nbr[(size_t)i * KNBR + k];
                    xs[tid] = feats[(size_t)nb * NCH + tid];
                }
                __syncthreads();
                if (tid < NCH) {
                    const float* Wk = fo_w + (size_t)k * NCH * NCH;
#pragma unroll 8
                    for (int j = 0; j < NCH; ++j)
                        acc += xs[j] * Wk[j * NCH + tid];
                }
                __syncthreads();
            }
            if (tid < NCH) xin[0][tid] = elu1(acc * fo_g[tid] + fo_b[tid]);
            else           xin[1][t]   = feats[(size_t)i * NCH + t];
            __syncthreads();

            // ---- layer 1: cls_out ----
            {
                const float* W = cls_out_w + (size_t)c * NCH * NCH;
                float v = 0.0f;
#pragma unroll 8
                for (int j = 0; j < NCH; ++j) v += xin[h][j] * W[j * NCH + t];
                v = elu1(v * cls_out_g[c * NCH + t] + cls_out_b[c * NCH + t]);
                hbuf[h][t] = v;
            }
            __syncthreads();
            // ---- layer 2: up ----
            {
                const float* W = up_w + (size_t)c * NCH * NCH;
                float v = 0.0f;
#pragma unroll 8
                for (int j = 0; j < NCH; ++j) v += hbuf[h][j] * W[j * NCH + t];
                v = elu1(v * up_g[c * NCH + t] + up_b[c * NCH + t]);
                ubuf[h][t] = v;
            }
            __syncthreads();
            // ---- layer 3: fuse (concat[hc, uc] @ W3) ----
            {
                const float* W = fuse_w + (size_t)c * 2 * NCH * NCH;
                float v = 0.0f;
#pragma unroll 8
                for (int j = 0; j < NCH; ++j) v += hbuf[h][j] * W[j * NCH + t];
#pragma unroll 8
                for (int j = 0; j < NCH; ++j) v += ubuf[h][j] * W[(NCH + j) * NCH + t];
                v = elu1(v * fuse_g[c * NCH + t] + fuse_b[c * NCH + t]);
                fbuf[h][t] = v;
            }
            __syncthreads();
            // ---- layer 4: expand ----
            {
                const float* W = exp_w + (size_t)c * NCH * NCH;
                float v = 0.0f;
#pragma unroll 8
                for (int j = 0; j < NCH; ++j) v += fbuf[h][j] * W[j * NCH + t];
                v = elu1(v * exp_g[c * NCH + t] + exp_b[c * NCH + t]);
                ebuf[h][t] = v;
            }
            __syncthreads();
            // ---- heads: [ctr(1), reg(6), cls(10)] = 17 ----
            if (t < 17) {
                float a = 0.0f;
                if (t == 0) {
                    for (int j = 0; j < NCH; ++j) a += ebuf[h][j] * ctr_w[j];
                } else if (t < 7) {
                    const int rr = t - 1;
                    for (int j = 0; j < NCH; ++j) a += ebuf[h][j] * reg_w[j * 6 + rr];
                    a = expf(scales[c] * a);
                } else {
                    const int q = t - 7;
                    for (int j = 0; j < NCH; ++j) a += ebuf[h][j] * cls_w[j * NCLS_ + q];
                    a += cls_b[q];
                }
                out[((size_t)c * 2 * N + (size_t)h * N + i) * 17 + t] = a;
            }
            __syncthreads();
        }
    }
}

extern "C" void kernel_launch(void* const* d_in, const int* in_sizes, int n_in,
                              void* d_out, int out_size, void* d_ws, size_t ws_size,
                              hipStream_t stream) {
    // setup_inputs() order:
    //  0 coords (unused)  1 feats  2 nbr  3 Wsem  4 bsem
    //  5..11 offset block (dead code: `voted` is deleted)
    // 12 fo_w 13 fo_g 14 fo_b  15-17 cls_out_*  18-20 up_*  21-23 fuse_*
    // 24-26 exp_*  27 ctr_w 28 reg_w 29 cls_w 30 cls_b 31 scales
    const float* feats = (const float*)d_in[1];
    const int*   nbr   = (const int*)d_in[2];
    const float* Wsem  = (const float*)d_in[3];
    const float* bsem  = (const float*)d_in[4];
    const float* fo_w  = (const float*)d_in[12];
    const float* fo_g  = (const float*)d_in[13];
    const float* fo_b  = (const float*)d_in[14];
    const float* cls_out_w = (const float*)d_in[15];
    const float* cls_out_g = (const float*)d_in[16];
    const float* cls_out_b = (const float*)d_in[17];
    const float* up_w  = (const float*)d_in[18];
    const float* up_g  = (const float*)d_in[19];
    const float* up_b  = (const float*)d_in[20];
    const float* fuse_w = (const float*)d_in[21];
    const float* fuse_g = (const float*)d_in[22];
    const float* fuse_b = (const float*)d_in[23];
    const float* exp_w = (const float*)d_in[24];
    const float* exp_g = (const float*)d_in[25];
    const float* exp_b = (const float*)d_in[26];
    const float* ctr_w = (const float*)d_in[27];
    const float* reg_w = (const float*)d_in[28];
    const float* cls_w = (const float*)d_in[29];
    const float* cls_b = (const float*)d_in[30];
    const float* scales = (const float*)d_in[31];

    const int N = in_sizes[1] / NCH;      // 65536
    float* out = (float*)d_out;

    fused_kernel<<<dim3(N / ROWS), dim3(256), 0, stream>>>(
        feats, nbr, Wsem, bsem,
        fo_w, fo_g, fo_b,
        cls_out_w, cls_out_g, cls_out_b,
        up_w, up_g, up_b,
        fuse_w, fuse_g, fuse_b,
        exp_w, exp_g, exp_b,
        ctr_w, reg_w, cls_w, cls_b, scales,
        out, N);
}

// Round 5
// 184.429 us; speedup vs baseline: 1.4630x; 1.0042x over previous
//
#include <hip/hip_runtime.h>
#include <math.h>

// CAGroup3DHead, fully fused single kernel (v2: latency-ordered + nt stores).
// Facts exploited (verified R0-R3, absmax==0):
//  (a) `voted`/offset-MLP branch is dead code (del voted).
//  (b) sem gating sigmoid(logit)>0.15 with bias -4.595 needs a +12.7-sigma
//      logit -> ~zero active rows; masked rows are EXACT zeros in the
//      reference (inputs zeroed before matmuls AND outputs multiplied by m2).
// One block = one 64-row chunk: issue its feats loads first (hide HBM
// latency behind the store stream), zero-fill its 20 output spans with
// nontemporal stores, compute 64x10 logits (wave-uniform scalar Wsem loads),
// block-uniform early exit; full fp32 chain only for active (class,row).

#define NCH   128
#define NCLS_ 10
#define KNBR  27
#define THRV  0.15f
#define ROWS  64

// native clang vector: __builtin_nontemporal_store rejects HIP_vector_type
typedef float nfloat4 __attribute__((ext_vector_type(4)));

__device__ __forceinline__ float elu1(float x) {
    return x > 0.0f ? x : expm1f(x);
}

__global__ __launch_bounds__(256) void fused_kernel(
    const float* __restrict__ feats, const int* __restrict__ nbr,
    const float* __restrict__ Wsem, const float* __restrict__ bsem,
    const float* __restrict__ fo_w, const float* __restrict__ fo_g, const float* __restrict__ fo_b,
    const float* __restrict__ cls_out_w, const float* __restrict__ cls_out_g, const float* __restrict__ cls_out_b,
    const float* __restrict__ up_w, const float* __restrict__ up_g, const float* __restrict__ up_b,
    const float* __restrict__ fuse_w, const float* __restrict__ fuse_g, const float* __restrict__ fuse_b,
    const float* __restrict__ exp_w, const float* __restrict__ exp_g, const float* __restrict__ exp_b,
    const float* __restrict__ ctr_w, const float* __restrict__ reg_w,
    const float* __restrict__ cls_w, const float* __restrict__ cls_b,
    const float* __restrict__ scales,
    float* __restrict__ out, int N)
{
    const int i0  = blockIdx.x * ROWS;
    const int tid = threadIdx.x;

    __shared__ float part[4][ROWS][11];   // [wave][row][class], pad 11
    __shared__ unsigned int rowbits[ROWS];
    __shared__ unsigned int anyword;

    if (tid == 0) anyword = 0u;

    // ---- 0) issue this lane's feats loads FIRST (in flight during the fill) ----
    const int lane = tid & 63;
    const int w    = __builtin_amdgcn_readfirstlane(tid >> 6);  // wave-uniform
    const float* fp = feats + (size_t)(i0 + lane) * NCH + w * 32;
    float4 fv4[8];
#pragma unroll
    for (int k = 0; k < 8; ++k) fv4[k] = ((const float4*)fp)[k];

    // ---- 1) zero-fill this chunk's 20 output spans (nontemporal: no L2 alloc) ----
    {
        const nfloat4 z4 = (nfloat4)(0.0f);
#pragma unroll
        for (int s = 0; s < 2 * NCLS_; ++s) {
            const int c = s >> 1, hh = s & 1;
            nfloat4* p = (nfloat4*)(out + ((size_t)c * 2 * N + (size_t)hh * N + i0) * 17);
#pragma unroll
            for (int idx = tid; idx < ROWS * 17 / 4; idx += 256)  // 272 f4 / span
                __builtin_nontemporal_store(z4, p + idx);
        }
    }

    // ---- 2) logits: wave w owns j-chunk [32w,32w+32) (uniform -> s_load) ----
    {
        const float* wp = Wsem + (size_t)(w * 32) * NCLS_;
        float acc[NCLS_];
#pragma unroll
        for (int c = 0; c < NCLS_; ++c) acc[c] = 0.0f;
#pragma unroll
        for (int k = 0; k < 8; ++k) {
            const float fr[4] = { fv4[k].x, fv4[k].y, fv4[k].z, fv4[k].w };
#pragma unroll
            for (int d = 0; d < 4; ++d) {
                const float* wrow = wp + (4 * k + d) * NCLS_;   // uniform -> s_load
#pragma unroll
                for (int c = 0; c < NCLS_; ++c) acc[c] += fr[d] * wrow[c];
            }
        }
#pragma unroll
        for (int c = 0; c < NCLS_; ++c) part[w][lane][c] = acc[c];
    }
    __syncthreads();

    // ---- 3) reduce -> per-row bits, block OR ----
    if (tid < ROWS) {
        unsigned int bits = 0u;
#pragma unroll
        for (int c = 0; c < NCLS_; ++c) {
            const float s = part[0][tid][c] + part[1][tid][c]
                          + part[2][tid][c] + part[3][tid][c] + bsem[c];
            const float p = 1.0f / (1.0f + expf(-s));
            if (p > THRV) bits |= (1u << c);
        }
        rowbits[tid] = bits;
        if (bits) atomicOr(&anyword, bits);
    }
    __syncthreads();
    const unsigned int any = anyword;
    if (any == 0u) return;   // block-uniform: the overwhelmingly common case

    // -------------- rare path: some (class,row) in this chunk is active --------------
    __shared__ float xs[NCH];
    __shared__ float xin[2][NCH];
    __shared__ float hbuf[2][NCH];
    __shared__ float ubuf[2][NCH];
    __shared__ float fbuf[2][NCH];
    __shared__ float ebuf[2][NCH];

    const int h = tid >> 7;   // 0: offset-features half, 1: feats half
    const int t = tid & 127;  // output channel

    for (int c = 0; c < NCLS_; ++c) {
        if (!((any >> c) & 1u)) continue;            // uniform
        for (int r = 0; r < ROWS; ++r) {
            if (!((rowbits[r] >> c) & 1u)) continue; // uniform (LDS broadcast)
            const int i = i0 + r;

            // ---- offset_features row i: 27-neighbor sparse conv + BN + ELU ----
            float acc = 0.0f;
            for (int k = 0; k < KNBR; ++k) {
                if (tid < NCH) {
                    const int nb = nbr[(size_t)i * KNBR + k];
                    xs[tid] = feats[(size_t)nb * NCH + tid];
                }
                __syncthreads();
                if (tid < NCH) {
                    const float* Wk = fo_w + (size_t)k * NCH * NCH;
#pragma unroll 8
                    for (int j = 0; j < NCH; ++j)
                        acc += xs[j] * Wk[j * NCH + tid];
                }
                __syncthreads();
            }
            if (tid < NCH) xin[0][tid] = elu1(acc * fo_g[tid] + fo_b[tid]);
            else           xin[1][t]   = feats[(size_t)i * NCH + t];
            __syncthreads();

            // ---- layer 1: cls_out ----
            {
                const float* W = cls_out_w + (size_t)c * NCH * NCH;
                float v = 0.0f;
#pragma unroll 8
                for (int j = 0; j < NCH; ++j) v += xin[h][j] * W[j * NCH + t];
                v = elu1(v * cls_out_g[c * NCH + t] + cls_out_b[c * NCH + t]);
                hbuf[h][t] = v;
            }
            __syncthreads();
            // ---- layer 2: up ----
            {
                const float* W = up_w + (size_t)c * NCH * NCH;
                float v = 0.0f;
#pragma unroll 8
                for (int j = 0; j < NCH; ++j) v += hbuf[h][j] * W[j * NCH + t];
                v = elu1(v * up_g[c * NCH + t] + up_b[c * NCH + t]);
                ubuf[h][t] = v;
            }
            __syncthreads();
            // ---- layer 3: fuse (concat[hc, uc] @ W3) ----
            {
                const float* W = fuse_w + (size_t)c * 2 * NCH * NCH;
                float v = 0.0f;
#pragma unroll 8
                for (int j = 0; j < NCH; ++j) v += hbuf[h][j] * W[j * NCH + t];
#pragma unroll 8
                for (int j = 0; j < NCH; ++j) v += ubuf[h][j] * W[(NCH + j) * NCH + t];
                v = elu1(v * fuse_g[c * NCH + t] + fuse_b[c * NCH + t]);
                fbuf[h][t] = v;
            }
            __syncthreads();
            // ---- layer 4: expand ----
            {
                const float* W = exp_w + (size_t)c * NCH * NCH;
                float v = 0.0f;
#pragma unroll 8
                for (int j = 0; j < NCH; ++j) v += fbuf[h][j] * W[j * NCH + t];
                v = elu1(v * exp_g[c * NCH + t] + exp_b[c * NCH + t]);
                ebuf[h][t] = v;
            }
            __syncthreads();
            // ---- heads: [ctr(1), reg(6), cls(10)] = 17 ----
            if (t < 17) {
                float a = 0.0f;
                if (t == 0) {
                    for (int j = 0; j < NCH; ++j) a += ebuf[h][j] * ctr_w[j];
                } else if (t < 7) {
                    const int rr = t - 1;
                    for (int j = 0; j < NCH; ++j) a += ebuf[h][j] * reg_w[j * 6 + rr];
                    a = expf(scales[c] * a);
                } else {
                    const int q = t - 7;
                    for (int j = 0; j < NCH; ++j) a += ebuf[h][j] * cls_w[j * NCLS_ + q];
                    a += cls_b[q];
                }
                out[((size_t)c * 2 * N + (size_t)h * N + i) * 17 + t] = a;
            }
            __syncthreads();
        }
    }
}

extern "C" void kernel_launch(void* const* d_in, const int* in_sizes, int n_in,
                              void* d_out, int out_size, void* d_ws, size_t ws_size,
                              hipStream_t stream) {
    // setup_inputs() order:
    //  0 coords (unused)  1 feats  2 nbr  3 Wsem  4 bsem
    //  5..11 offset block (dead code: `voted` is deleted)
    // 12 fo_w 13 fo_g 14 fo_b  15-17 cls_out_*  18-20 up_*  21-23 fuse_*
    // 24-26 exp_*  27 ctr_w 28 reg_w 29 cls_w 30 cls_b 31 scales
    const float* feats = (const float*)d_in[1];
    const int*   nbr   = (const int*)d_in[2];
    const float* Wsem  = (const float*)d_in[3];
    const float* bsem  = (const float*)d_in[4];
    const float* fo_w  = (const float*)d_in[12];
    const float* fo_g  = (const float*)d_in[13];
    const float* fo_b  = (const float*)d_in[14];
    const float* cls_out_w = (const float*)d_in[15];
    const float* cls_out_g = (const float*)d_in[16];
    const float* cls_out_b = (const float*)d_in[17];
    const float* up_w  = (const float*)d_in[18];
    const float* up_g  = (const float*)d_in[19];
    const float* up_b  = (const float*)d_in[20];
    const float* fuse_w = (const float*)d_in[21];
    const float* fuse_g = (const float*)d_in[22];
    const float* fuse_b = (const float*)d_in[23];
    const float* exp_w = (const float*)d_in[24];
    const float* exp_g = (const float*)d_in[25];
    const float* exp_b = (const float*)d_in[26];
    const float* ctr_w = (const float*)d_in[27];
    const float* reg_w = (const float*)d_in[28];
    const float* cls_w = (const float*)d_in[29];
    const float* cls_b = (const float*)d_in[30];
    const float* scales = (const float*)d_in[31];

    const int N = in_sizes[1] / NCH;      // 65536
    float* out = (float*)d_out;

    fused_kernel<<<dim3(N / ROWS), dim3(256), 0, stream>>>(
        feats, nbr, Wsem, bsem,
        fo_w, fo_g, fo_b,
        cls_out_w, cls_out_g, cls_out_b,
        up_w, up_g, up_b,
        fuse_w, fuse_g, fuse_b,
        exp_w, exp_g, exp_b,
        ctr_w, reg_w, cls_w, cls_b, scales,
        out, N);
}